// Round 2
// baseline (222.178 us; speedup 1.0000x reference)
//
#include <hip/hip_runtime.h>

#define NG 4096
#define RELAX 0.1875f

__device__ __forceinline__ float linf(int i) { return -1.0f + (2.0f/63.0f)*(float)i; }

__global__ __launch_bounds__(256) void gm_preprocess(
    const float* __restrict__ xyz, const float* __restrict__ scal,
    const float* __restrict__ rot, const float* __restrict__ opac,
    float4* __restrict__ posopa, float4* __restrict__ invrec)
{
  __shared__ float s_mn[3][256];
  __shared__ float s_mx[3][256];
  __shared__ float s_c[4]; // cx, cy, cz, scale
  const int tid = threadIdx.x;
  float mn0=1e10f, mn1=1e10f, mn2=1e10f;
  float mx0=-1e10f, mx1=-1e10f, mx2=-1e10f;
  for (int g = tid; g < NG; g += 256) {
    float o = opac[g];
    float sig = 1.0f/(1.0f + __expf(-o));
    if (sig > 0.005f) {
      float x = xyz[3*g+0], y = xyz[3*g+1], z = xyz[3*g+2];
      mn0 = fminf(mn0,x); mn1 = fminf(mn1,y); mn2 = fminf(mn2,z);
      mx0 = fmaxf(mx0,x); mx1 = fmaxf(mx1,y); mx2 = fmaxf(mx2,z);
    }
  }
  s_mn[0][tid]=mn0; s_mn[1][tid]=mn1; s_mn[2][tid]=mn2;
  s_mx[0][tid]=mx0; s_mx[1][tid]=mx1; s_mx[2][tid]=mx2;
  __syncthreads();
  for (int s = 128; s > 0; s >>= 1) {
    if (tid < s) {
      #pragma unroll
      for (int k = 0; k < 3; ++k) {
        s_mn[k][tid] = fminf(s_mn[k][tid], s_mn[k][tid+s]);
        s_mx[k][tid] = fmaxf(s_mx[k][tid], s_mx[k][tid+s]);
      }
    }
    __syncthreads();
  }
  if (tid == 0) {
    float r0 = s_mx[0][0]-s_mn[0][0];
    float r1 = s_mx[1][0]-s_mn[1][0];
    float r2 = s_mx[2][0]-s_mn[2][0];
    float rmax = fmaxf(r0, fmaxf(r1, r2));
    s_c[0] = (s_mn[0][0]+s_mx[0][0])*0.5f;
    s_c[1] = (s_mn[1][0]+s_mx[1][0])*0.5f;
    s_c[2] = (s_mn[2][0]+s_mx[2][0])*0.5f;
    s_c[3] = 1.8f/rmax;
  }
  __syncthreads();
  const float cx=s_c[0], cy=s_c[1], cz=s_c[2], scale=s_c[3];
  for (int g = tid; g < NG; g += 256) {
    float o = opac[g];
    float sig = 1.0f/(1.0f + __expf(-o));
    float opa = (sig > 0.005f) ? sig : 0.0f;
    float xs = (xyz[3*g+0]-cx)*scale;
    float ys = (xyz[3*g+1]-cy)*scale;
    float zs = (xyz[3*g+2]-cz)*scale;
    float sdx = __expf(scal[3*g+0])*scale;
    float sdy = __expf(scal[3*g+1])*scale;
    float sdz = __expf(scal[3*g+2])*scale;
    float qr=rot[4*g+0], qx=rot[4*g+1], qy=rot[4*g+2], qz=rot[4*g+3];
    float qn = 1.0f/sqrtf(qr*qr+qx*qx+qy*qy+qz*qz);
    qr*=qn; qx*=qn; qy*=qn; qz*=qn;
    float R00 = 1.0f-2.0f*(qy*qy+qz*qz), R01 = 2.0f*(qx*qy-qr*qz), R02 = 2.0f*(qx*qz+qr*qy);
    float R10 = 2.0f*(qx*qy+qr*qz), R11 = 1.0f-2.0f*(qx*qx+qz*qz), R12 = 2.0f*(qy*qz-qr*qx);
    float R20 = 2.0f*(qx*qz-qr*qy), R21 = 2.0f*(qy*qz+qr*qx), R22 = 1.0f-2.0f*(qx*qx+qy*qy);
    // L = R * diag-col(stds): L[i][j] = R[i][j]*std[j]
    float L00=R00*sdx, L01=R01*sdy, L02=R02*sdz;
    float L10=R10*sdx, L11=R11*sdy, L12=R12*sdz;
    float L20=R20*sdx, L21=R21*sdy, L22=R22*sdz;
    // C = L L^T
    float a = L00*L00+L01*L01+L02*L02;
    float b = L00*L10+L01*L11+L02*L12;
    float c = L00*L20+L01*L21+L02*L22;
    float d = L10*L10+L11*L11+L12*L12;
    float e = L10*L20+L11*L21+L12*L22;
    float f = L20*L20+L21*L21+L22*L22;
    float det = a*d*f + 2.0f*e*c*b - e*e*a - c*c*d - b*b*f + 1e-24f;
    float idt = 1.0f/det;
    float ia=(d*f-e*e)*idt, ib=(e*c-b*f)*idt, ic=(e*b-c*d)*idt;
    float id=(a*f-c*c)*idt, ie=(b*c-e*a)*idt, iff=(a*d-b*b)*idt;
    posopa[g] = make_float4(xs, ys, zs, opa);
    invrec[2*g+0] = make_float4(ia, ib, ic, id);
    invrec[2*g+1] = make_float4(ie, iff, 0.0f, 0.0f);
  }
}

__global__ __launch_bounds__(256) void gm_evaluate(
    const float4* __restrict__ posopa, const float4* __restrict__ invrec,
    float* __restrict__ out)
{
  __shared__ int   s_cnt;
  __shared__ int   s_idx[NG];   // 16 KB, cannot overflow (<= NG entries)
  __shared__ float s_acc[256];
  const int tid = threadIdx.x;
  const int b  = blockIdx.x;
  const int bi = b >> 8, bj = (b >> 4) & 15, bk = b & 15;
  const float vminx = linf(bi*4)   - RELAX, vmaxx = linf(bi*4+3) + RELAX;
  const float vminy = linf(bj*4)   - RELAX, vmaxy = linf(bj*4+3) + RELAX;
  const float vminz = linf(bk*4)   - RELAX, vmaxz = linf(bk*4+3) + RELAX;
  if (tid == 0) s_cnt = 0;
  __syncthreads();
  // cull: 256 threads scan 4096 gaussians (coalesced float4 reads)
  #pragma unroll
  for (int c = 0; c < NG/256; ++c) {
    int g = c*256 + tid;
    float4 p = posopa[g];
    if (p.w > 0.0f &&
        p.x > vminx && p.x < vmaxx &&
        p.y > vminy && p.y < vmaxy &&
        p.z > vminz && p.z < vmaxz) {
      int slot = atomicAdd(&s_cnt, 1);
      s_idx[slot] = g;
    }
  }
  __syncthreads();
  const int n = s_cnt;
  // eval: 4 threads per point; each wave shares `part` -> wave-uniform list loads
  const int p    = tid & 63;
  const int part = tid >> 6;
  const int sx = p >> 4, sy = (p >> 2) & 3, sz = p & 3;
  const float ptx = linf(bi*4+sx), pty = linf(bj*4+sy), ptz = linf(bk*4+sz);
  float acc = 0.0f;
  for (int j = part; j < n; j += 4) {
    int g = s_idx[j];
    float4 P  = posopa[g];
    float4 I0 = invrec[2*g+0];
    float4 I1 = invrec[2*g+1];
    float px = ptx - P.x, py = pty - P.y, pz = ptz - P.z;
    // I0 = (inv_a, inv_b, inv_c, inv_d); I1 = (inv_e, inv_f, -, -)
    float power = -0.5f*(px*px*I0.x + py*py*I0.w + pz*pz*I1.y)
                  - px*py*I0.y - px*pz*I0.z - py*pz*I1.x;
    if (power <= 0.0f) acc += P.w * __expf(power);
  }
  s_acc[tid] = acc;
  __syncthreads();
  if (tid < 64) {
    float v = s_acc[tid] + s_acc[tid+64] + s_acc[tid+128] + s_acc[tid+192];
    out[(bi*4+sx)*4096 + (bj*4+sy)*64 + (bk*4+sz)] = v;
  }
}

extern "C" void kernel_launch(void* const* d_in, const int* in_sizes, int n_in,
                              void* d_out, int out_size, void* d_ws, size_t ws_size,
                              hipStream_t stream) {
  const float* xyz  = (const float*)d_in[0];
  const float* scal = (const float*)d_in[1];
  const float* rot  = (const float*)d_in[2];
  const float* opac = (const float*)d_in[3];
  float* out = (float*)d_out;
  float4* posopa = (float4*)d_ws;          // NG float4  (64 KB)
  float4* invrec = posopa + NG;            // 2*NG float4 (128 KB)
  gm_preprocess<<<1, 256, 0, stream>>>(xyz, scal, rot, opac, posopa, invrec);
  gm_evaluate<<<4096, 256, 0, stream>>>(posopa, invrec, out);
}

// Round 3
// 144.265 us; speedup vs baseline: 1.5401x; 1.5401x over previous
//
#include <hip/hip_runtime.h>

#define NG 4096
#define RELAX 0.1875f
#define CHUNK 512

__device__ __forceinline__ float linf(int i) { return -1.0f + (2.0f/63.0f)*(float)i; }

// ---- Kernel A: masked min/max reduction -> center/scale (1 block) ----
__global__ __launch_bounds__(256) void gm_reduce(
    const float* __restrict__ xyz, const float* __restrict__ opac,
    float4* __restrict__ cs)
{
  __shared__ float s_mn[3][256];
  __shared__ float s_mx[3][256];
  const int tid = threadIdx.x;
  float mn0=1e10f, mn1=1e10f, mn2=1e10f;
  float mx0=-1e10f, mx1=-1e10f, mx2=-1e10f;
  for (int g = tid; g < NG; g += 256) {
    float o = opac[g];
    float sig = 1.0f/(1.0f + __expf(-o));
    if (sig > 0.005f) {
      float x = xyz[3*g+0], y = xyz[3*g+1], z = xyz[3*g+2];
      mn0 = fminf(mn0,x); mn1 = fminf(mn1,y); mn2 = fminf(mn2,z);
      mx0 = fmaxf(mx0,x); mx1 = fmaxf(mx1,y); mx2 = fmaxf(mx2,z);
    }
  }
  s_mn[0][tid]=mn0; s_mn[1][tid]=mn1; s_mn[2][tid]=mn2;
  s_mx[0][tid]=mx0; s_mx[1][tid]=mx1; s_mx[2][tid]=mx2;
  __syncthreads();
  for (int s = 128; s > 0; s >>= 1) {
    if (tid < s) {
      #pragma unroll
      for (int k = 0; k < 3; ++k) {
        s_mn[k][tid] = fminf(s_mn[k][tid], s_mn[k][tid+s]);
        s_mx[k][tid] = fmaxf(s_mx[k][tid], s_mx[k][tid+s]);
      }
    }
    __syncthreads();
  }
  if (tid == 0) {
    float r0 = s_mx[0][0]-s_mn[0][0];
    float r1 = s_mx[1][0]-s_mn[1][0];
    float r2 = s_mx[2][0]-s_mn[2][0];
    float rmax = fmaxf(r0, fmaxf(r1, r2));
    *cs = make_float4((s_mn[0][0]+s_mx[0][0])*0.5f,
                      (s_mn[1][0]+s_mx[1][0])*0.5f,
                      (s_mn[2][0]+s_mx[2][0])*0.5f,
                      1.8f/rmax);
  }
}

// ---- Kernel B: per-gaussian transform + covariance inverse (16 blocks) ----
__global__ __launch_bounds__(256) void gm_transform(
    const float* __restrict__ xyz, const float* __restrict__ scal,
    const float* __restrict__ rot, const float* __restrict__ opac,
    const float4* __restrict__ cs,
    float4* __restrict__ posopa, float4* __restrict__ invrec)
{
  const int g = blockIdx.x*256 + threadIdx.x;
  const float4 c = *cs;
  const float cx=c.x, cy=c.y, cz=c.z, scale=c.w;
  float o = opac[g];
  float sig = 1.0f/(1.0f + __expf(-o));
  float opa = (sig > 0.005f) ? sig : 0.0f;
  float xs = (xyz[3*g+0]-cx)*scale;
  float ys = (xyz[3*g+1]-cy)*scale;
  float zs = (xyz[3*g+2]-cz)*scale;
  float sdx = __expf(scal[3*g+0])*scale;
  float sdy = __expf(scal[3*g+1])*scale;
  float sdz = __expf(scal[3*g+2])*scale;
  float qr=rot[4*g+0], qx=rot[4*g+1], qy=rot[4*g+2], qz=rot[4*g+3];
  float qn = 1.0f/sqrtf(qr*qr+qx*qx+qy*qy+qz*qz);
  qr*=qn; qx*=qn; qy*=qn; qz*=qn;
  float R00 = 1.0f-2.0f*(qy*qy+qz*qz), R01 = 2.0f*(qx*qy-qr*qz), R02 = 2.0f*(qx*qz+qr*qy);
  float R10 = 2.0f*(qx*qy+qr*qz), R11 = 1.0f-2.0f*(qx*qx+qz*qz), R12 = 2.0f*(qy*qz-qr*qx);
  float R20 = 2.0f*(qx*qz-qr*qy), R21 = 2.0f*(qy*qz+qr*qx), R22 = 1.0f-2.0f*(qx*qx+qy*qy);
  float L00=R00*sdx, L01=R01*sdy, L02=R02*sdz;
  float L10=R10*sdx, L11=R11*sdy, L12=R12*sdz;
  float L20=R20*sdx, L21=R21*sdy, L22=R22*sdz;
  float a = L00*L00+L01*L01+L02*L02;
  float b = L00*L10+L01*L11+L02*L12;
  float cc= L00*L20+L01*L21+L02*L22;
  float d = L10*L10+L11*L11+L12*L12;
  float e = L10*L20+L11*L21+L12*L22;
  float f = L20*L20+L21*L21+L22*L22;
  float det = a*d*f + 2.0f*e*cc*b - e*e*a - cc*cc*d - b*b*f + 1e-24f;
  float idt = 1.0f/det;
  float ia=(d*f-e*e)*idt, ib=(e*cc-b*f)*idt, ic=(e*b-cc*d)*idt;
  float id=(a*f-cc*cc)*idt, ie=(b*cc-e*a)*idt, iff=(a*d-b*b)*idt;
  posopa[g] = make_float4(xs, ys, zs, opa);
  invrec[2*g+0] = make_float4(ia, ib, ic, id);
  invrec[2*g+1] = make_float4(ie, iff, 0.0f, 0.0f);
}

// ---- Kernel C: per-block cull + eval with chunked LDS data staging ----
__global__ __launch_bounds__(256) void gm_evaluate(
    const float4* __restrict__ posopa, const float4* __restrict__ invrec,
    float* __restrict__ out)
{
  __shared__ int    s_cnt;
  __shared__ float4 s_g[CHUNK*3];   // 24 KB: (pos,opa),(ia,ib,ic,id),(ie,if,-,-)
  __shared__ float  s_acc[256];
  const int tid = threadIdx.x;
  const int b  = blockIdx.x;
  const int bi = b >> 8, bj = (b >> 4) & 15, bk = b & 15;
  const float vminx = linf(bi*4) - RELAX, vmaxx = linf(bi*4+3) + RELAX;
  const float vminy = linf(bj*4) - RELAX, vmaxy = linf(bj*4+3) + RELAX;
  const float vminz = linf(bk*4) - RELAX, vmaxz = linf(bk*4+3) + RELAX;
  const int p    = tid & 63;
  const int part = tid >> 6;
  const int sx = p >> 4, sy = (p >> 2) & 3, sz = p & 3;
  const float ptx = linf(bi*4+sx), pty = linf(bj*4+sy), ptz = linf(bk*4+sz);
  float acc = 0.0f;

  for (int c0 = 0; c0 < NG; c0 += CHUNK) {
    if (tid == 0) s_cnt = 0;
    __syncthreads();
    // scan: 256 threads test CHUNK gaussians (coalesced float4); survivors
    // append full record to LDS (<= CHUNK per chunk -> no overflow possible)
    #pragma unroll
    for (int t = 0; t < CHUNK/256; ++t) {
      int g = c0 + t*256 + tid;
      float4 P = posopa[g];
      if (P.w > 0.0f &&
          P.x > vminx && P.x < vmaxx &&
          P.y > vminy && P.y < vmaxy &&
          P.z > vminz && P.z < vmaxz) {
        int slot = atomicAdd(&s_cnt, 1);
        s_g[3*slot+0] = P;
        s_g[3*slot+1] = invrec[2*g+0];
        s_g[3*slot+2] = invrec[2*g+1];
      }
    }
    __syncthreads();
    const int n = s_cnt;
    // eval: wave-uniform LDS broadcasts, 4-way partial split over survivors
    for (int j = part; j < n; j += 4) {
      float4 P  = s_g[3*j+0];
      float4 I0 = s_g[3*j+1];
      float4 I1 = s_g[3*j+2];
      float px = ptx - P.x, py = pty - P.y, pz = ptz - P.z;
      float power = -0.5f*(px*px*I0.x + py*py*I0.w + pz*pz*I1.y)
                    - px*py*I0.y - px*pz*I0.z - py*pz*I1.x;
      if (power <= 0.0f) acc += P.w * __expf(power);
    }
    __syncthreads();
  }

  s_acc[tid] = acc;
  __syncthreads();
  if (tid < 64) {
    float v = s_acc[tid] + s_acc[tid+64] + s_acc[tid+128] + s_acc[tid+192];
    out[(bi*4+sx)*4096 + (bj*4+sy)*64 + (bk*4+sz)] = v;
  }
}

extern "C" void kernel_launch(void* const* d_in, const int* in_sizes, int n_in,
                              void* d_out, int out_size, void* d_ws, size_t ws_size,
                              hipStream_t stream) {
  const float* xyz  = (const float*)d_in[0];
  const float* scal = (const float*)d_in[1];
  const float* rot  = (const float*)d_in[2];
  const float* opac = (const float*)d_in[3];
  float* out = (float*)d_out;
  float4* posopa = (float4*)d_ws;          // NG float4   (64 KB)
  float4* invrec = posopa + NG;            // 2*NG float4 (128 KB)
  float4* cs     = invrec + 2*NG;          // 1 float4
  gm_reduce   <<<1,    256, 0, stream>>>(xyz, opac, cs);
  gm_transform<<<16,   256, 0, stream>>>(xyz, scal, rot, opac, cs, posopa, invrec);
  gm_evaluate <<<4096, 256, 0, stream>>>(posopa, invrec, out);
}

// Round 4
// 119.514 us; speedup vs baseline: 1.8590x; 1.2071x over previous
//
#include <hip/hip_runtime.h>

#define NG 4096
#define RELAX 0.1875f
#define BINCAP NG
#define CHUNK 512
#define EV_THREADS 512

__device__ __forceinline__ float linf(int i) { return -1.0f + (2.0f/63.0f)*(float)i; }
// center-first axis permutation: {7,8,6,9,5,10,4,11,3,12,2,13,1,14,0,15}
__device__ __forceinline__ int cperm(int i) { return (i & 1) ? 7 + ((i+1)>>1) : 7 - (i>>1); }

// ---- A: partial masked min/max (16 blocks x 256 = 1 thread/gaussian) ----
__global__ __launch_bounds__(256) void gm_reduce1(
    const float* __restrict__ xyz, const float* __restrict__ opac,
    float4* __restrict__ pmin, float4* __restrict__ pmax)
{
  __shared__ float s_mn[3][256];
  __shared__ float s_mx[3][256];
  const int tid = threadIdx.x;
  const int g = blockIdx.x*256 + tid;
  float o = opac[g];
  float sig = 1.0f/(1.0f + __expf(-o));
  bool keep = sig > 0.005f;
  float x = xyz[3*g+0], y = xyz[3*g+1], z = xyz[3*g+2];
  s_mn[0][tid] = keep ? x :  1e10f;
  s_mn[1][tid] = keep ? y :  1e10f;
  s_mn[2][tid] = keep ? z :  1e10f;
  s_mx[0][tid] = keep ? x : -1e10f;
  s_mx[1][tid] = keep ? y : -1e10f;
  s_mx[2][tid] = keep ? z : -1e10f;
  __syncthreads();
  for (int s = 128; s > 0; s >>= 1) {
    if (tid < s) {
      #pragma unroll
      for (int k = 0; k < 3; ++k) {
        s_mn[k][tid] = fminf(s_mn[k][tid], s_mn[k][tid+s]);
        s_mx[k][tid] = fmaxf(s_mx[k][tid], s_mx[k][tid+s]);
      }
    }
    __syncthreads();
  }
  if (tid == 0) {
    pmin[blockIdx.x] = make_float4(s_mn[0][0], s_mn[1][0], s_mn[2][0], 0.0f);
    pmax[blockIdx.x] = make_float4(s_mx[0][0], s_mx[1][0], s_mx[2][0], 0.0f);
  }
}

// ---- B: finalize center/scale (1 wave) ----
__global__ void gm_reduce2(const float4* __restrict__ pmin,
                           const float4* __restrict__ pmax,
                           float4* __restrict__ cs)
{
  const int lane = threadIdx.x;
  float mn0=1e10f, mn1=1e10f, mn2=1e10f;
  float mx0=-1e10f, mx1=-1e10f, mx2=-1e10f;
  if (lane < 16) {
    float4 a = pmin[lane], b = pmax[lane];
    mn0=a.x; mn1=a.y; mn2=a.z; mx0=b.x; mx1=b.y; mx2=b.z;
  }
  #pragma unroll
  for (int s = 8; s > 0; s >>= 1) {
    mn0 = fminf(mn0, __shfl_down(mn0, s));
    mn1 = fminf(mn1, __shfl_down(mn1, s));
    mn2 = fminf(mn2, __shfl_down(mn2, s));
    mx0 = fmaxf(mx0, __shfl_down(mx0, s));
    mx1 = fmaxf(mx1, __shfl_down(mx1, s));
    mx2 = fmaxf(mx2, __shfl_down(mx2, s));
  }
  if (lane == 0) {
    float rmax = fmaxf(mx0-mn0, fmaxf(mx1-mn1, mx2-mn2));
    *cs = make_float4((mn0+mx0)*0.5f, (mn1+mx1)*0.5f, (mn2+mx2)*0.5f, 1.8f/rmax);
  }
}

// ---- C: transform + inverse covariance, pre-scaled for eval ----
// stores I0=(-0.5ia, -ib, -ic, -0.5id), I1=(-ie, -0.5if, 0, 0) so that
// power = px^2*I0.x + py^2*I0.w + pz^2*I1.y + px*py*I0.y + px*pz*I0.z + py*pz*I1.x
__global__ __launch_bounds__(256) void gm_transform(
    const float* __restrict__ xyz, const float* __restrict__ scal,
    const float* __restrict__ rot, const float* __restrict__ opac,
    const float4* __restrict__ cs,
    float4* __restrict__ posopa, float4* __restrict__ invrec)
{
  const int g = blockIdx.x*256 + threadIdx.x;
  const float4 c = *cs;
  float o = opac[g];
  float sig = 1.0f/(1.0f + __expf(-o));
  float opa = (sig > 0.005f) ? sig : 0.0f;
  float xs = (xyz[3*g+0]-c.x)*c.w;
  float ys = (xyz[3*g+1]-c.y)*c.w;
  float zs = (xyz[3*g+2]-c.z)*c.w;
  float sdx = __expf(scal[3*g+0])*c.w;
  float sdy = __expf(scal[3*g+1])*c.w;
  float sdz = __expf(scal[3*g+2])*c.w;
  float qr=rot[4*g+0], qx=rot[4*g+1], qy=rot[4*g+2], qz=rot[4*g+3];
  float qn = 1.0f/sqrtf(qr*qr+qx*qx+qy*qy+qz*qz);
  qr*=qn; qx*=qn; qy*=qn; qz*=qn;
  float R00 = 1.0f-2.0f*(qy*qy+qz*qz), R01 = 2.0f*(qx*qy-qr*qz), R02 = 2.0f*(qx*qz+qr*qy);
  float R10 = 2.0f*(qx*qy+qr*qz), R11 = 1.0f-2.0f*(qx*qx+qz*qz), R12 = 2.0f*(qy*qz-qr*qx);
  float R20 = 2.0f*(qx*qz-qr*qy), R21 = 2.0f*(qy*qz+qr*qx), R22 = 1.0f-2.0f*(qx*qx+qy*qy);
  float L00=R00*sdx, L01=R01*sdy, L02=R02*sdz;
  float L10=R10*sdx, L11=R11*sdy, L12=R12*sdz;
  float L20=R20*sdx, L21=R21*sdy, L22=R22*sdz;
  float a = L00*L00+L01*L01+L02*L02;
  float b = L00*L10+L01*L11+L02*L12;
  float cc= L00*L20+L01*L21+L02*L22;
  float d = L10*L10+L11*L11+L12*L12;
  float e = L10*L20+L11*L21+L12*L22;
  float f = L20*L20+L21*L21+L22*L22;
  float det = a*d*f + 2.0f*e*cc*b - e*e*a - cc*cc*d - b*b*f + 1e-24f;
  float idt = 1.0f/det;
  float ia=(d*f-e*e)*idt, ib=(e*cc-b*f)*idt, ic=(e*b-cc*d)*idt;
  float id=(a*f-cc*cc)*idt, ie=(b*cc-e*a)*idt, iff=(a*d-b*b)*idt;
  posopa[g] = make_float4(xs, ys, zs, opa);
  invrec[2*g+0] = make_float4(-0.5f*ia, -ib, -ic, -0.5f*id);
  invrec[2*g+1] = make_float4(-ie, -0.5f*iff, 0.0f, 0.0f);
}

// ---- D: 2D (bi,bj) binning: per-bin index lists ----
__global__ __launch_bounds__(256) void gm_bin(
    const float4* __restrict__ posopa,
    int* __restrict__ bincnt, unsigned short* __restrict__ binidx)
{
  __shared__ int s_cnt;
  __shared__ unsigned short s_idx[NG];   // 8 KB
  const int tid = threadIdx.x;
  const int b = blockIdx.x;
  const int bi = b >> 4, bj = b & 15;
  const float vminx = linf(bi*4) - RELAX, vmaxx = linf(bi*4+3) + RELAX;
  const float vminy = linf(bj*4) - RELAX, vmaxy = linf(bj*4+3) + RELAX;
  if (tid == 0) s_cnt = 0;
  __syncthreads();
  #pragma unroll
  for (int t = 0; t < NG/256; ++t) {
    int g = t*256 + tid;
    float4 P = posopa[g];
    if (P.w > 0.0f &&
        P.x > vminx && P.x < vmaxx &&
        P.y > vminy && P.y < vmaxy) {
      int slot = atomicAdd(&s_cnt, 1);
      s_idx[slot] = (unsigned short)g;
    }
  }
  __syncthreads();
  const int n = s_cnt;
  if (tid == 0) bincnt[b] = n;
  for (int t = tid; t < n; t += 256) binidx[b*BINCAP + t] = s_idx[t];
}

// ---- E: eval from bin list (z-filter + LDS-staged records) ----
__global__ __launch_bounds__(EV_THREADS) void gm_evaluate(
    const float4* __restrict__ posopa, const float4* __restrict__ invrec,
    const int* __restrict__ bincnt, const unsigned short* __restrict__ binidx,
    float* __restrict__ out)
{
  __shared__ int    s_cnt;
  __shared__ float4 s_g[CHUNK*3];       // 24 KB
  __shared__ float  s_acc[EV_THREADS];  // 2 KB
  const int tid = threadIdx.x;
  const int b = blockIdx.x;
  const int bi = cperm(b >> 8), bj = cperm((b >> 4) & 15), bk = cperm(b & 15);
  const float vminz = linf(bk*4) - RELAX, vmaxz = linf(bk*4+3) + RELAX;
  const int p    = tid & 63;
  const int part = tid >> 6;            // 0..7
  const int sx = p >> 4, sy = (p >> 2) & 3, sz = p & 3;
  const float ptx = linf(bi*4+sx), pty = linf(bj*4+sy), ptz = linf(bk*4+sz);
  const unsigned short* mylist = binidx + (bi*16 + bj)*BINCAP;
  const int nxy = bincnt[bi*16 + bj];
  float acc = 0.0f;

  for (int c0 = 0; c0 < nxy; c0 += CHUNK) {
    if (tid == 0) s_cnt = 0;
    __syncthreads();
    const int lim = min(nxy - c0, CHUNK);
    if (tid < lim) {                    // EV_THREADS == CHUNK: 1 test/thread
      int g = mylist[c0 + tid];
      float4 P = posopa[g];
      if (P.z > vminz && P.z < vmaxz) {
        int slot = atomicAdd(&s_cnt, 1);
        s_g[3*slot+0] = P;
        s_g[3*slot+1] = invrec[2*g+0];
        s_g[3*slot+2] = invrec[2*g+1];
      }
    }
    __syncthreads();
    const int n = s_cnt;
    #pragma unroll 4
    for (int j = part; j < n; j += 8) {
      float4 P  = s_g[3*j+0];
      float4 I0 = s_g[3*j+1];
      float4 I1 = s_g[3*j+2];
      float px = ptx - P.x, py = pty - P.y, pz = ptz - P.z;
      float power = px*px*I0.x + py*py*I0.w + pz*pz*I1.y
                  + px*py*I0.y + px*pz*I0.z + py*pz*I1.x;
      power = (power > 0.0f) ? -1e10f : power;   // branchless
      acc += P.w * __expf(power);
    }
    __syncthreads();
  }

  s_acc[tid] = acc;
  __syncthreads();
  if (tid < 64) {
    float v = 0.0f;
    #pragma unroll
    for (int w = 0; w < 8; ++w) v += s_acc[tid + w*64];
    out[(bi*4+sx)*4096 + (bj*4+sy)*64 + (bk*4+sz)] = v;
  }
}

// ---- fallback eval (no binning) if ws is too small ----
__global__ __launch_bounds__(EV_THREADS) void gm_evaluate_nobin(
    const float4* __restrict__ posopa, const float4* __restrict__ invrec,
    float* __restrict__ out)
{
  __shared__ int    s_cnt;
  __shared__ float4 s_g[CHUNK*3];
  __shared__ float  s_acc[EV_THREADS];
  const int tid = threadIdx.x;
  const int b = blockIdx.x;
  const int bi = cperm(b >> 8), bj = cperm((b >> 4) & 15), bk = cperm(b & 15);
  const float vminx = linf(bi*4) - RELAX, vmaxx = linf(bi*4+3) + RELAX;
  const float vminy = linf(bj*4) - RELAX, vmaxy = linf(bj*4+3) + RELAX;
  const float vminz = linf(bk*4) - RELAX, vmaxz = linf(bk*4+3) + RELAX;
  const int p    = tid & 63;
  const int part = tid >> 6;
  const int sx = p >> 4, sy = (p >> 2) & 3, sz = p & 3;
  const float ptx = linf(bi*4+sx), pty = linf(bj*4+sy), ptz = linf(bk*4+sz);
  float acc = 0.0f;
  for (int c0 = 0; c0 < NG; c0 += CHUNK) {
    if (tid == 0) s_cnt = 0;
    __syncthreads();
    int g = c0 + tid;
    float4 P = posopa[g];
    if (P.w > 0.0f &&
        P.x > vminx && P.x < vmaxx &&
        P.y > vminy && P.y < vmaxy &&
        P.z > vminz && P.z < vmaxz) {
      int slot = atomicAdd(&s_cnt, 1);
      s_g[3*slot+0] = P;
      s_g[3*slot+1] = invrec[2*g+0];
      s_g[3*slot+2] = invrec[2*g+1];
    }
    __syncthreads();
    const int n = s_cnt;
    #pragma unroll 4
    for (int j = part; j < n; j += 8) {
      float4 Pq = s_g[3*j+0];
      float4 I0 = s_g[3*j+1];
      float4 I1 = s_g[3*j+2];
      float px = ptx - Pq.x, py = pty - Pq.y, pz = ptz - Pq.z;
      float power = px*px*I0.x + py*py*I0.w + pz*pz*I1.y
                  + px*py*I0.y + px*pz*I0.z + py*pz*I1.x;
      power = (power > 0.0f) ? -1e10f : power;
      acc += Pq.w * __expf(power);
    }
    __syncthreads();
  }
  s_acc[tid] = acc;
  __syncthreads();
  if (tid < 64) {
    float v = 0.0f;
    #pragma unroll
    for (int w = 0; w < 8; ++w) v += s_acc[tid + w*64];
    out[(bi*4+sx)*4096 + (bj*4+sy)*64 + (bk*4+sz)] = v;
  }
}

extern "C" void kernel_launch(void* const* d_in, const int* in_sizes, int n_in,
                              void* d_out, int out_size, void* d_ws, size_t ws_size,
                              hipStream_t stream) {
  const float* xyz  = (const float*)d_in[0];
  const float* scal = (const float*)d_in[1];
  const float* rot  = (const float*)d_in[2];
  const float* opac = (const float*)d_in[3];
  float* out = (float*)d_out;
  char* ws = (char*)d_ws;
  float4* posopa = (float4*)(ws);                       //  64 KB
  float4* invrec = (float4*)(ws + 65536);               // 128 KB
  float4* cs     = (float4*)(ws + 65536 + 131072);      //  16 B
  float4* pmin   = cs + 1;                              // 256 B
  float4* pmax   = pmin + 16;                           // 256 B
  int*    bincnt = (int*)(pmax + 16);                   //   1 KB
  unsigned short* binidx = (unsigned short*)(bincnt + 256); // 2 MB
  const size_t needed = 65536 + 131072 + 16 + 512 + 1024 + (size_t)256*BINCAP*2;

  gm_reduce1  <<<16, 256, 0, stream>>>(xyz, opac, pmin, pmax);
  gm_reduce2  <<<1,   64, 0, stream>>>(pmin, pmax, cs);
  gm_transform<<<16, 256, 0, stream>>>(xyz, scal, rot, opac, cs, posopa, invrec);
  if (ws_size >= needed) {
    gm_bin     <<<256, 256, 0, stream>>>(posopa, bincnt, binidx);
    gm_evaluate<<<4096, EV_THREADS, 0, stream>>>(posopa, invrec, bincnt, binidx, out);
  } else {
    gm_evaluate_nobin<<<4096, EV_THREADS, 0, stream>>>(posopa, invrec, out);
  }
}